// Round 2
// baseline (2157.888 us; speedup 1.0000x reference)
//
#include <hip/hip_runtime.h>
#include <hip/hip_bf16.h>

// QuantiZ: e = codebook[4096,1024] @ proj_w[256,1024]^T + proj_b
//          zidx[t] = argmin_k ||z_t - e_k||  (== argmax softmax path in ref)
//          quant[t] = e[zidx[t]]
// d_out is FLOAT32: [ zidx as float (32768) | quant (32768*256) ].

#define K_CODES 4096
#define CDIM    256
#define IDIM    1024
#define NTOK    32768

// ---------------- Kernel A: e = cb @ pw^T + pb  (f32, 64x64 tile) ------------
extern "C" __global__ __launch_bounds__(256)
void proj_gemm(const float* __restrict__ cb, const float* __restrict__ pw,
               const float* __restrict__ pb, float* __restrict__ e) {
  __shared__ float As[64][33];
  __shared__ float Bs[64][33];
  const int tid = threadIdx.x;
  const int tx = tid & 15, ty = tid >> 4;
  const int m0 = blockIdx.y << 6;   // code rows
  const int n0 = blockIdx.x << 6;   // out cols (c-dim)
  const int r  = tid >> 2;          // 0..63 staging row
  const int c8 = (tid & 3) << 3;    // 0,8,16,24
  float acc[4][4] = {};
  for (int k0 = 0; k0 < IDIM; k0 += 32) {
    float4 a0 = *(const float4*)&cb[(m0 + r) * IDIM + k0 + c8];
    float4 a1 = *(const float4*)&cb[(m0 + r) * IDIM + k0 + c8 + 4];
    float4 b0 = *(const float4*)&pw[(n0 + r) * IDIM + k0 + c8];
    float4 b1 = *(const float4*)&pw[(n0 + r) * IDIM + k0 + c8 + 4];
    __syncthreads();
    As[r][c8+0]=a0.x; As[r][c8+1]=a0.y; As[r][c8+2]=a0.z; As[r][c8+3]=a0.w;
    As[r][c8+4]=a1.x; As[r][c8+5]=a1.y; As[r][c8+6]=a1.z; As[r][c8+7]=a1.w;
    Bs[r][c8+0]=b0.x; Bs[r][c8+1]=b0.y; Bs[r][c8+2]=b0.z; Bs[r][c8+3]=b0.w;
    Bs[r][c8+4]=b1.x; Bs[r][c8+5]=b1.y; Bs[r][c8+6]=b1.z; Bs[r][c8+7]=b1.w;
    __syncthreads();
    #pragma unroll
    for (int kk = 0; kk < 32; ++kk) {
      float av[4], bv[4];
      #pragma unroll
      for (int i = 0; i < 4; ++i) av[i] = As[ty*4 + i][kk];
      #pragma unroll
      for (int j = 0; j < 4; ++j) bv[j] = Bs[tx*4 + j][kk];
      #pragma unroll
      for (int i = 0; i < 4; ++i)
        #pragma unroll
        for (int j = 0; j < 4; ++j)
          acc[i][j] += av[i] * bv[j];
    }
  }
  #pragma unroll
  for (int i = 0; i < 4; ++i)
    #pragma unroll
    for (int j = 0; j < 4; ++j)
      e[(m0 + ty*4 + i) * CDIM + n0 + tx*4 + j] = acc[i][j] + pb[n0 + tx*4 + j];
}

// ---------------- Kernel A2: e2[k] = sum_c e[k][c]^2 ------------------------
extern "C" __global__ __launch_bounds__(256)
void compute_e2(const float* __restrict__ e, float* __restrict__ e2) {
  const int gid  = blockIdx.x * 256 + threadIdx.x;
  const int w    = gid >> 6;              // row (4096 waves total)
  const int lane = threadIdx.x & 63;
  float4 v = *(const float4*)&e[w * CDIM + (lane << 2)];
  float s = v.x*v.x + v.y*v.y + v.z*v.z + v.w*v.w;
  #pragma unroll
  for (int off = 32; off > 0; off >>= 1) s += __shfl_down(s, off, 64);
  if (lane == 0) e2[w] = s;
}

// ---------------- Kernel B: fused score + argmin ----------------------------
// score(t,k) = e2[k] - 2 * dot(z_t, e_k); argmin over k, first-index ties.
extern "C" __global__ __launch_bounds__(256)
void score_argmin(const float* __restrict__ z, const float* __restrict__ e,
                  const float* __restrict__ e2g, int* __restrict__ zidx_i,
                  float* __restrict__ zidx_f) {
  union Sh {
    struct { float Zs[128][36]; float Es[128][36]; } a; // 36 KB
    struct { float v[128][17]; int idx[128][17]; } r;   // overlay, used after barrier
  };
  __shared__ Sh sh;
  const int tid = threadIdx.x;
  const int tx = tid & 15, ty = tid >> 4;   // tx 0..15 (codes), ty 0..15 (tokens)
  const int t0 = blockIdx.x << 7;           // 128 tokens per block
  const int sr = tid >> 3;                  // staging row 0..31
  const int sc = (tid & 7) << 2;            // staging col 0..28
  float bestv[8];
  int   besti[8];
  #pragma unroll
  for (int i = 0; i < 8; ++i) { bestv[i] = 3.4e38f; besti[i] = 0; }

  for (int cc = 0; cc < 32; ++cc) {         // 128-code chunks
    float acc[8][8] = {};
    for (int kc = 0; kc < 256; kc += 32) {  // dim slices
      float4 zv[4], ev[4];
      #pragma unroll
      for (int p = 0; p < 4; ++p) {
        zv[p] = *(const float4*)&z[(t0 + sr + 32*p) * CDIM + kc + sc];
        ev[p] = *(const float4*)&e[(cc*128 + sr + 32*p) * CDIM + kc + sc];
      }
      __syncthreads();
      #pragma unroll
      for (int p = 0; p < 4; ++p) {
        *(float4*)&sh.a.Zs[sr + 32*p][sc] = zv[p];
        *(float4*)&sh.a.Es[sr + 32*p][sc] = ev[p];
      }
      __syncthreads();
      #pragma unroll
      for (int dd = 0; dd < 32; dd += 4) {
        float4 za[8], eb[8];
        #pragma unroll
        for (int i = 0; i < 8; ++i) za[i] = *(const float4*)&sh.a.Zs[ty + 16*i][dd];
        #pragma unroll
        for (int j = 0; j < 8; ++j) eb[j] = *(const float4*)&sh.a.Es[tx + 16*j][dd];
        #pragma unroll
        for (int i = 0; i < 8; ++i)
          #pragma unroll
          for (int j = 0; j < 8; ++j) {
            acc[i][j] += za[i].x * eb[j].x;
            acc[i][j] += za[i].y * eb[j].y;
            acc[i][j] += za[i].z * eb[j].z;
            acc[i][j] += za[i].w * eb[j].w;
          }
      }
      __syncthreads();
    }
    #pragma unroll
    for (int j = 0; j < 8; ++j) {
      const int code = cc*128 + tx + 16*j;
      const float ee = e2g[code];
      #pragma unroll
      for (int i = 0; i < 8; ++i) {
        const float s = ee - 2.0f * acc[i][j];
        if (s < bestv[i]) { bestv[i] = s; besti[i] = code; }  // strict <: first idx
      }
    }
  }
  __syncthreads();
  #pragma unroll
  for (int i = 0; i < 8; ++i) {
    const int t = ty + 16*i;
    sh.r.v[t][tx]   = bestv[i];
    sh.r.idx[t][tx] = besti[i];
  }
  __syncthreads();
  if (tid < 128) {
    float bv = sh.r.v[tid][0];
    int   bi = sh.r.idx[tid][0];
    #pragma unroll
    for (int x = 1; x < 16; ++x) {
      const float vv = sh.r.v[tid][x];
      const int   ii = sh.r.idx[tid][x];
      if (vv < bv || (vv == bv && ii < bi)) { bv = vv; bi = ii; }
    }
    zidx_i[t0 + tid] = bi;
    zidx_f[t0 + tid] = (float)bi;
  }
}

// ---------------- Kernel C: quant = e[zidx]  (f32 out) ----------------------
extern "C" __global__ __launch_bounds__(256)
void gather_quant(const float* __restrict__ e, const int* __restrict__ zidx,
                  float* __restrict__ q) {
  const int gid = blockIdx.x * 256 + threadIdx.x;
  const int t = gid >> 6;          // 64 threads per token
  const int c = (gid & 63) << 2;   // 4 elems per thread
  const int idx = zidx[t];
  const float4 v = *(const float4*)&e[idx * CDIM + c];
  *(float4*)&q[t * CDIM + c] = v;
}

// ---------------- launch ----------------------------------------------------
extern "C" void kernel_launch(void* const* d_in, const int* in_sizes, int n_in,
                              void* d_out, int out_size, void* d_ws, size_t ws_size,
                              hipStream_t stream) {
  const float* encode = (const float*)d_in[0];   // [8,64,64,256] -> z[32768,256]
  const float* cb     = (const float*)d_in[1];   // [4096,1024]
  const float* pw     = (const float*)d_in[2];   // [256,1024]
  const float* pb     = (const float*)d_in[3];   // [256]

  float* e  = (float*)d_ws;                      // 4 MB
  float* e2 = e + (size_t)K_CODES * CDIM;        // 16 KB
  int*   zi = (int*)(e2 + K_CODES);              // 128 KB

  float* out     = (float*)d_out;                // f32 output buffer
  float* zidx_f  = out;                          // [32768] zidx as float
  float* quant_f = out + NTOK;                   // [32768*256] quant f32

  proj_gemm<<<dim3(CDIM/64, K_CODES/64), 256, 0, stream>>>(cb, pw, pb, e);
  compute_e2<<<(K_CODES*64)/256, 256, 0, stream>>>(e, e2);
  score_argmin<<<NTOK/128, 256, 0, stream>>>(encode, e, e2, zi, zidx_f);
  gather_quant<<<(NTOK*64)/256, 256, 0, stream>>>(e, zi, quant_f);
}

// Round 4
// 343.392 us; speedup vs baseline: 6.2840x; 6.2840x over previous
//
#include <hip/hip_runtime.h>
#include <hip/hip_bf16.h>

// QuantiZ: e = codebook[4096,1024] @ proj_w[256,1024]^T + proj_b
//          zidx[t] = argmin_k ||z_t - e_k||, quant[t] = e[zidx[t]]
// d_out FLOAT32: [ zidx as float (32768) | quant (32768*256) ].
// Score GEMM done as exact split-bf16 (hi+lo), 4 terms concatenated on K=1024,
// via v_mfma_f32_16x16x32_bf16.

#define K_CODES 4096
#define CDIM    256
#define IDIM    1024
#define NTOK    32768

typedef __attribute__((ext_vector_type(8))) short short8;
typedef __attribute__((ext_vector_type(4))) float f32x4;

__device__ __forceinline__ unsigned short f32_to_bf16_rne(float f) {
  union { float f; unsigned int u; } x; x.f = f;
  unsigned int r = x.u + 0x7FFFu + ((x.u >> 16) & 1u);
  return (unsigned short)(r >> 16);
}
__device__ __forceinline__ float bf16_to_f32(unsigned short h) {
  union { unsigned int u; float f; } x; x.u = ((unsigned int)h) << 16;
  return x.f;
}
__device__ __forceinline__ void gll16(const void* g, void* l) {
  __builtin_amdgcn_global_load_lds(
      (const __attribute__((address_space(1))) unsigned int*)g,
      (__attribute__((address_space(3))) unsigned int*)l, 16, 0, 0);
}

// ---------------- Kernel A: e = cb @ pw^T + pb  (f32, 64x64 tile) ------------
extern "C" __global__ __launch_bounds__(256)
void proj_gemm(const float* __restrict__ cb, const float* __restrict__ pw,
               const float* __restrict__ pb, float* __restrict__ e) {
  __shared__ float As[64][33];
  __shared__ float Bs[64][33];
  const int tid = threadIdx.x;
  const int tx = tid & 15, ty = tid >> 4;
  const int m0 = blockIdx.y << 6;
  const int n0 = blockIdx.x << 6;
  const int r  = tid >> 2;
  const int c8 = (tid & 3) << 3;
  float acc[4][4] = {};
  for (int k0 = 0; k0 < IDIM; k0 += 32) {
    float4 a0 = *(const float4*)&cb[(m0 + r) * IDIM + k0 + c8];
    float4 a1 = *(const float4*)&cb[(m0 + r) * IDIM + k0 + c8 + 4];
    float4 b0 = *(const float4*)&pw[(n0 + r) * IDIM + k0 + c8];
    float4 b1 = *(const float4*)&pw[(n0 + r) * IDIM + k0 + c8 + 4];
    __syncthreads();
    As[r][c8+0]=a0.x; As[r][c8+1]=a0.y; As[r][c8+2]=a0.z; As[r][c8+3]=a0.w;
    As[r][c8+4]=a1.x; As[r][c8+5]=a1.y; As[r][c8+6]=a1.z; As[r][c8+7]=a1.w;
    Bs[r][c8+0]=b0.x; Bs[r][c8+1]=b0.y; Bs[r][c8+2]=b0.z; Bs[r][c8+3]=b0.w;
    Bs[r][c8+4]=b1.x; Bs[r][c8+5]=b1.y; Bs[r][c8+6]=b1.z; Bs[r][c8+7]=b1.w;
    __syncthreads();
    #pragma unroll
    for (int kk = 0; kk < 32; ++kk) {
      float av[4], bv[4];
      #pragma unroll
      for (int i = 0; i < 4; ++i) av[i] = As[ty*4 + i][kk];
      #pragma unroll
      for (int j = 0; j < 4; ++j) bv[j] = Bs[tx*4 + j][kk];
      #pragma unroll
      for (int i = 0; i < 4; ++i)
        #pragma unroll
        for (int j = 0; j < 4; ++j)
          acc[i][j] += av[i] * bv[j];
    }
  }
  #pragma unroll
  for (int i = 0; i < 4; ++i)
    #pragma unroll
    for (int j = 0; j < 4; ++j)
      e[(m0 + ty*4 + i) * CDIM + n0 + tx*4 + j] = acc[i][j] + pb[n0 + tx*4 + j];
}

// -------- Kernel A2: split e into Ect[16][4096][32] bf16 + e2[k] ------------
// kb 0-7 = hi windows (cols kb*32..), kb 8-15 = lo windows.
extern "C" __global__ __launch_bounds__(256)
void split_e(const float* __restrict__ e, unsigned short* __restrict__ Ect,
             float* __restrict__ e2) {
  const int gid = blockIdx.x * 256 + threadIdx.x;
  const int row = gid >> 6;          // 4096 rows, one wave per row
  const int l   = threadIdx.x & 63;
  const float4 v = *(const float4*)&e[row * CDIM + (l << 2)];
  unsigned short h[4], lo[4];
  float vv[4] = {v.x, v.y, v.z, v.w};
  #pragma unroll
  for (int c = 0; c < 4; ++c) {
    h[c]  = f32_to_bf16_rne(vv[c]);
    lo[c] = f32_to_bf16_rne(vv[c] - bf16_to_f32(h[c]));
  }
  const int kb = l >> 3;             // window 0..7
  const int co = (l << 2) & 31;      // col in window
  *(ushort4*)&Ect[((size_t)kb       * K_CODES + row) * 32 + co] = *(ushort4*)h;
  *(ushort4*)&Ect[((size_t)(kb + 8) * K_CODES + row) * 32 + co] = *(ushort4*)lo;
  float s = vv[0]*vv[0] + vv[1]*vv[1] + vv[2]*vv[2] + vv[3]*vv[3];
  #pragma unroll
  for (int off = 32; off > 0; off >>= 1) s += __shfl_down(s, off, 64);
  if (l == 0) e2[row] = s;
}

// ---------------- Kernel B: MFMA score + argmin -----------------------------
// LDS: Z [128][512] bf16 (hi cols 0-255 = ka 0-7, lo = ka 8-15), row XOR-swz.
//      E tile dbuf 2 x [256 codes][32 k] bf16, granule swz via pre-swz source.
extern "C" __global__ __launch_bounds__(512, 2)
void score_mfma(const float* __restrict__ z, const unsigned short* __restrict__ Ect,
                const float* __restrict__ e2g, int* __restrict__ zidx_i,
                float* __restrict__ zidx_f) {
  extern __shared__ __align__(16) char smem[];   // 160 KB
  char* Zb = smem;                                // 131072 B
  char* EbBase = smem + 131072;                   // 2 x 16384 B

  const int tid = threadIdx.x;
  const int l   = tid & 63;
  const int w   = tid >> 6;          // wave 0..7
  const int wr  = w >> 2;            // token half (0..1)
  const int wc  = w & 3;             // code quarter (0..3)
  const int t0  = blockIdx.x << 7;   // 128 tokens per block

  // ---- prologue: issue E slab for step 0 (kb=0, cc=0) ----
  {
    const char* slab = (const char*)Ect;         // kb=0, codes 0..255
    char* dst = EbBase + w * 2048;
    #pragma unroll
    for (int q = 0; q < 2; ++q) {
      const int code_local = 32*w + 16*q + (l >> 2);
      const int gsrc = (l & 3) ^ ((l >> 3) & 3);
      gll16(slab + (size_t)code_local * 64 + gsrc * 16, dst + q * 1024);
    }
  }

  // ---- stage Z (hi/lo bf16) into LDS with row XOR swizzle ----
  {
    const int r  = tid >> 2;              // token row 0..127
    const int cs = (tid & 3) << 6;        // source col base 0/64/128/192
    const int sw = (r & 7) << 4;
    #pragma unroll
    for (int i = 0; i < 8; ++i) {
      const float4 v0 = *(const float4*)&z[(size_t)(t0 + r) * CDIM + cs + i*8];
      const float4 v1 = *(const float4*)&z[(size_t)(t0 + r) * CDIM + cs + i*8 + 4];
      float vv[8] = {v0.x,v0.y,v0.z,v0.w,v1.x,v1.y,v1.z,v1.w};
      unsigned int hp[4], lp[4];
      #pragma unroll
      for (int c = 0; c < 4; ++c) {
        unsigned short h0 = f32_to_bf16_rne(vv[2*c]);
        unsigned short h1 = f32_to_bf16_rne(vv[2*c+1]);
        unsigned short l0 = f32_to_bf16_rne(vv[2*c]   - bf16_to_f32(h0));
        unsigned short l1 = f32_to_bf16_rne(vv[2*c+1] - bf16_to_f32(h1));
        hp[c] = (unsigned int)h0 | ((unsigned int)h1 << 16);
        lp[c] = (unsigned int)l0 | ((unsigned int)l1 << 16);
      }
      const int ih = (((cs + i*8) << 1) ^ sw);
      *(uint4*)(Zb + (size_t)r * 1024 + ih)       = *(uint4*)hp;
      *(uint4*)(Zb + (size_t)r * 1024 + ih + 512) = *(uint4*)lp;
    }
  }
  __syncthreads();   // drains gll (vmcnt) + Z writes

  f32x4 acc[4][4];
  #pragma unroll
  for (int i = 0; i < 4; ++i)
    #pragma unroll
    for (int j = 0; j < 4; ++j) acc[i][j] = (f32x4){0.f,0.f,0.f,0.f};
  float bestv[4][4];
  int   besti[4][4];
  #pragma unroll
  for (int i = 0; i < 4; ++i)
    #pragma unroll
    for (int r = 0; r < 4; ++r) { bestv[i][r] = 3.4e38f; besti[i][r] = 0; }
  float e2v[4];

  const int lsw  = (l & 7) << 4;               // Z read swizzle bits
  const int bsw  = ((l & 15) >> 1) & 3;        // E granule swizzle
  const int g    = l >> 4;

  for (int s = 0; s < 512; ++s) {
    const int st = s & 31, cc = s >> 5;
    if (st == 0) {
      #pragma unroll
      for (int j = 0; j < 4; ++j)
        e2v[j] = e2g[cc*256 + wc*64 + j*16 + (l & 15)];
    }
    // issue next E slab into other buffer
    if (s + 1 < 512) {
      const int s1 = s + 1, st1 = s1 & 31, cc1 = s1 >> 5;
      const int kb1 = st1 & 15;
      const char* slab = (const char*)Ect +
          ((size_t)kb1 * K_CODES + (size_t)cc1 * 256) * 64;
      char* dst = EbBase + (s1 & 1) * 16384 + w * 2048;
      #pragma unroll
      for (int q = 0; q < 2; ++q) {
        const int code_local = 32*w + 16*q + (l >> 2);
        const int gsrc = (l & 3) ^ ((l >> 3) & 3);
        gll16(slab + (size_t)code_local * 64 + gsrc * 16, dst + q * 1024);
      }
    }
    // fragment reads
    const int ka = (st & 7) | ((st & 16) >> 1);
    const char* Ebc = EbBase + (s & 1) * 16384;
    short8 a[4], b[4];
    #pragma unroll
    for (int i = 0; i < 4; ++i) {
      const int row = wr*64 + i*16 + (l & 15);
      a[i] = *(const short8*)(Zb + (size_t)row * 1024 + ((ka*64 + (g << 4)) ^ lsw));
    }
    #pragma unroll
    for (int j = 0; j < 4; ++j) {
      const int code_local = wc*64 + j*16 + (l & 15);
      b[j] = *(const short8*)(Ebc + (size_t)code_local * 64 + ((g ^ bsw) << 4));
    }
    #pragma unroll
    for (int i = 0; i < 4; ++i)
      #pragma unroll
      for (int j = 0; j < 4; ++j)
        acc[i][j] = __builtin_amdgcn_mfma_f32_16x16x32_bf16(a[i], b[j], acc[i][j], 0, 0, 0);
    // per-cc epilogue: scores -> running argmin, reset acc
    if (st == 31) {
      #pragma unroll
      for (int j = 0; j < 4; ++j) {
        const int code = cc*256 + wc*64 + j*16 + (l & 15);
        #pragma unroll
        for (int i = 0; i < 4; ++i) {
          #pragma unroll
          for (int r = 0; r < 4; ++r) {
            const float sc = e2v[j] - 2.0f * acc[i][j][r];
            if (sc < bestv[i][r]) { bestv[i][r] = sc; besti[i][r] = code; }
          }
          acc[i][j] = (f32x4){0.f,0.f,0.f,0.f};
        }
      }
    }
    __syncthreads();
  }

  // ---- final argmin reduce: 16 lanes (code dim) then 4 wc waves ----
  struct RP { float v; int i; };
  RP* red = (RP*)(smem + 131072);    // [128][4], E buffers dead
  #pragma unroll
  for (int i = 0; i < 4; ++i)
    #pragma unroll
    for (int r = 0; r < 4; ++r) {
      float v = bestv[i][r]; int bi = besti[i][r];
      #pragma unroll
      for (int m = 1; m < 16; m <<= 1) {
        const float ov = __shfl_xor(v, m, 64);
        const int   oi = __shfl_xor(bi, m, 64);
        if (ov < v || (ov == v && oi < bi)) { v = ov; bi = oi; }
      }
      if ((l & 15) == 0) {
        const int tl = wr*64 + i*16 + g*4 + r;
        red[tl*4 + wc].v = v; red[tl*4 + wc].i = bi;
      }
    }
  __syncthreads();
  if (tid < 128) {
    float v = red[tid*4].v; int bi = red[tid*4].i;
    #pragma unroll
    for (int x = 1; x < 4; ++x) {
      const float ov = red[tid*4 + x].v; const int oi = red[tid*4 + x].i;
      if (ov < v || (ov == v && oi < bi)) { v = ov; bi = oi; }
    }
    zidx_i[t0 + tid] = bi;
    zidx_f[t0 + tid] = (float)bi;
  }
}

// ---------------- Kernel C: quant = e[zidx]  (f32 out) ----------------------
extern "C" __global__ __launch_bounds__(256)
void gather_quant(const float* __restrict__ e, const int* __restrict__ zidx,
                  float* __restrict__ q) {
  const int gid = blockIdx.x * 256 + threadIdx.x;
  const int t = gid >> 6;
  const int c = (gid & 63) << 2;
  const int idx = zidx[t];
  const float4 v = *(const float4*)&e[(size_t)idx * CDIM + c];
  *(float4*)&q[(size_t)t * CDIM + c] = v;
}

// ---------------- launch ----------------------------------------------------
extern "C" void kernel_launch(void* const* d_in, const int* in_sizes, int n_in,
                              void* d_out, int out_size, void* d_ws, size_t ws_size,
                              hipStream_t stream) {
  const float* encode = (const float*)d_in[0];
  const float* cb     = (const float*)d_in[1];
  const float* pw     = (const float*)d_in[2];
  const float* pb     = (const float*)d_in[3];

  float* e  = (float*)d_ws;                           // 4 MB
  float* e2 = e + (size_t)K_CODES * CDIM;             // 16 KB
  int*   zi = (int*)(e2 + K_CODES);                   // 128 KB
  unsigned short* Ect = (unsigned short*)(zi + NTOK); // 4 MB bf16 tiles

  float* out     = (float*)d_out;
  float* zidx_f  = out;
  float* quant_f = out + NTOK;

  (void)hipFuncSetAttribute((const void*)score_mfma,
                            hipFuncAttributeMaxDynamicSharedMemorySize, 163840);

  proj_gemm<<<dim3(CDIM/64, K_CODES/64), 256, 0, stream>>>(cb, pw, pb, e);
  split_e<<<(K_CODES*64)/256, 256, 0, stream>>>(e, Ect, e2);
  score_mfma<<<NTOK/128, 512, 163840, stream>>>(encode, Ect, e2, zi, zidx_f);
  gather_quant<<<(NTOK*64)/256, 256, 0, stream>>>(e, zi, quant_f);
}

// Round 5
// 268.979 us; speedup vs baseline: 8.0225x; 1.2766x over previous
//
#include <hip/hip_runtime.h>
#include <hip/hip_bf16.h>

// QuantiZ: e = codebook[4096,1024] @ proj_w[256,1024]^T + proj_b
//          zidx[t] = argmin_k ||z_t - e_k||, quant[t] = e[zidx[t]]
// d_out FLOAT32: [ zidx as float (32768) | quant (32768*256) ].
// Score GEMM: exact split-bf16 (hi+lo), 4 terms, v_mfma_f32_16x16x32_bf16.
// R5: E fragments fragment-linear in global (coalesced direct-to-reg loads),
//     barrier-free K-loop, term-factored 64-MFMA inner body.

#define K_CODES 4096
#define CDIM    256
#define IDIM    1024
#define NTOK    32768

typedef __attribute__((ext_vector_type(8))) short short8;
typedef __attribute__((ext_vector_type(4))) float f32x4;

__device__ __forceinline__ unsigned short f32_to_bf16_rne(float f) {
  union { float f; unsigned int u; } x; x.f = f;
  unsigned int r = x.u + 0x7FFFu + ((x.u >> 16) & 1u);
  return (unsigned short)(r >> 16);
}
__device__ __forceinline__ float bf16_to_f32(unsigned short h) {
  union { unsigned int u; float f; } x; x.u = ((unsigned int)h) << 16;
  return x.f;
}

// ---------------- Kernel A: e = cb @ pw^T + pb  (f32, 64x64 tile) ------------
extern "C" __global__ __launch_bounds__(256)
void proj_gemm(const float* __restrict__ cb, const float* __restrict__ pw,
               const float* __restrict__ pb, float* __restrict__ e) {
  __shared__ float As[64][33];
  __shared__ float Bs[64][33];
  const int tid = threadIdx.x;
  const int tx = tid & 15, ty = tid >> 4;
  const int m0 = blockIdx.y << 6;
  const int n0 = blockIdx.x << 6;
  const int r  = tid >> 2;
  const int c8 = (tid & 3) << 3;
  float acc[4][4] = {};
  for (int k0 = 0; k0 < IDIM; k0 += 32) {
    float4 a0 = *(const float4*)&cb[(m0 + r) * IDIM + k0 + c8];
    float4 a1 = *(const float4*)&cb[(m0 + r) * IDIM + k0 + c8 + 4];
    float4 b0 = *(const float4*)&pw[(n0 + r) * IDIM + k0 + c8];
    float4 b1 = *(const float4*)&pw[(n0 + r) * IDIM + k0 + c8 + 4];
    __syncthreads();
    As[r][c8+0]=a0.x; As[r][c8+1]=a0.y; As[r][c8+2]=a0.z; As[r][c8+3]=a0.w;
    As[r][c8+4]=a1.x; As[r][c8+5]=a1.y; As[r][c8+6]=a1.z; As[r][c8+7]=a1.w;
    Bs[r][c8+0]=b0.x; Bs[r][c8+1]=b0.y; Bs[r][c8+2]=b0.z; Bs[r][c8+3]=b0.w;
    Bs[r][c8+4]=b1.x; Bs[r][c8+5]=b1.y; Bs[r][c8+6]=b1.z; Bs[r][c8+7]=b1.w;
    __syncthreads();
    #pragma unroll
    for (int kk = 0; kk < 32; ++kk) {
      float av[4], bv[4];
      #pragma unroll
      for (int i = 0; i < 4; ++i) av[i] = As[ty*4 + i][kk];
      #pragma unroll
      for (int j = 0; j < 4; ++j) bv[j] = Bs[tx*4 + j][kk];
      #pragma unroll
      for (int i = 0; i < 4; ++i)
        #pragma unroll
        for (int j = 0; j < 4; ++j)
          acc[i][j] += av[i] * bv[j];
    }
  }
  #pragma unroll
  for (int i = 0; i < 4; ++i)
    #pragma unroll
    for (int j = 0; j < 4; ++j)
      e[(m0 + ty*4 + i) * CDIM + n0 + tx*4 + j] = acc[i][j] + pb[n0 + tx*4 + j];
}

// -------- Kernel A2: split e into fragment-linear Ect + e2[k] ---------------
// Ect layout: frag(kb 0..15, ct 0..255) = 1024 B at ((kb*256 + ct)*64 + lf)*16,
// where lane lf = g*16 + cl holds granule g (k elems 8g..8g+7) of code ct*16+cl.
// kb 0-7 = hi windows, 8-15 = lo windows.
extern "C" __global__ __launch_bounds__(256)
void split_e(const float* __restrict__ e, unsigned short* __restrict__ Ect,
             float* __restrict__ e2) {
  const int gid = blockIdx.x * 256 + threadIdx.x;
  const int row = gid >> 6;          // 4096 rows, one wave per row
  const int l   = threadIdx.x & 63;
  const float4 v = *(const float4*)&e[(size_t)row * CDIM + (l << 2)];
  unsigned short h[4], lo[4];
  float vv[4] = {v.x, v.y, v.z, v.w};
  #pragma unroll
  for (int c = 0; c < 4; ++c) {
    h[c]  = f32_to_bf16_rne(vv[c]);
    lo[c] = f32_to_bf16_rne(vv[c] - bf16_to_f32(h[c]));
  }
  const int kb   = l >> 3;           // window 0..7
  const int g    = (l >> 1) & 3;     // granule in window
  const int half = l & 1;            // 4-elem half of granule
  const int ct   = row >> 4;
  const int cl   = row & 15;
  const size_t fi = ((size_t)(kb * 256 + ct) * 64 + g * 16 + cl) * 8 + half * 4;
  const size_t fo = ((size_t)((kb + 8) * 256 + ct) * 64 + g * 16 + cl) * 8 + half * 4;
  *(ushort4*)&Ect[fi] = *(ushort4*)h;
  *(ushort4*)&Ect[fo] = *(ushort4*)lo;
  float s = vv[0]*vv[0] + vv[1]*vv[1] + vv[2]*vv[2] + vv[3]*vv[3];
  #pragma unroll
  for (int off = 32; off > 0; off >>= 1) s += __shfl_down(s, off, 64);
  if (l == 0) e2[row] = s;
}

// ---------------- Kernel B: MFMA score + argmin (barrier-free loop) ---------
// LDS: Z [128 rows][1024 B] bf16 (hi bytes 0-511, lo 512-1023), XOR-swizzled.
// E fragments loaded global->reg, coalesced (fragment-linear layout).
extern "C" __global__ __launch_bounds__(512, 2)
void score_mfma(const float* __restrict__ z, const unsigned short* __restrict__ Ect,
                const float* __restrict__ e2g, int* __restrict__ zidx_i,
                float* __restrict__ zidx_f) {
  extern __shared__ __align__(16) char smem[];   // 128 KB Z + 4 KB reduce
  char* Zb = smem;

  const int tid = threadIdx.x;
  const int l   = tid & 63;
  const int w   = tid >> 6;          // wave 0..7
  const int wr  = w >> 2;            // token half (0..1)
  const int wc  = w & 3;             // code quarter (0..3)
  const int t0  = blockIdx.x << 7;   // 128 tokens per block

  // ---- stage Z (hi/lo bf16) into LDS with row XOR swizzle ----
  {
    const int r  = tid >> 2;              // token row 0..127
    const int cs = (tid & 3) << 6;        // source col base 0/64/128/192
    const int sw = (r & 7) << 4;
    #pragma unroll
    for (int i = 0; i < 8; ++i) {
      const float4 v0 = *(const float4*)&z[(size_t)(t0 + r) * CDIM + cs + i*8];
      const float4 v1 = *(const float4*)&z[(size_t)(t0 + r) * CDIM + cs + i*8 + 4];
      float vv[8] = {v0.x,v0.y,v0.z,v0.w,v1.x,v1.y,v1.z,v1.w};
      unsigned int hp[4], lp[4];
      #pragma unroll
      for (int c = 0; c < 4; ++c) {
        unsigned short h0 = f32_to_bf16_rne(vv[2*c]);
        unsigned short h1 = f32_to_bf16_rne(vv[2*c+1]);
        unsigned short l0 = f32_to_bf16_rne(vv[2*c]   - bf16_to_f32(h0));
        unsigned short l1 = f32_to_bf16_rne(vv[2*c+1] - bf16_to_f32(h1));
        hp[c] = (unsigned int)h0 | ((unsigned int)h1 << 16);
        lp[c] = (unsigned int)l0 | ((unsigned int)l1 << 16);
      }
      const int ih = (((cs + i*8) << 1) ^ sw);
      *(uint4*)(Zb + (size_t)r * 1024 + ih)       = *(uint4*)hp;
      *(uint4*)(Zb + (size_t)r * 1024 + ih + 512) = *(uint4*)lp;
    }
  }
  __syncthreads();   // Z ready; no further barriers until final reduce

  float bestv[4][4];
  int   besti[4][4];
  #pragma unroll
  for (int i = 0; i < 4; ++i)
    #pragma unroll
    for (int r = 0; r < 4; ++r) { bestv[i][r] = 3.4e38f; besti[i][r] = 0; }

  const int cl  = l & 15;
  const int g   = l >> 4;
  const int lsw = (l & 7) << 4;                  // Z read swizzle bits

  // per-lane E base: frag(kb, ct) byte offset = kb*262144 + ct*1024 + l*16
  const char* ebase = (const char*)Ect + (size_t)l * 16 + (size_t)wc * 4096;

  for (int cc = 0; cc < 16; ++cc) {              // 256-code chunks
    f32x4 acc[4][4];
    #pragma unroll
    for (int i = 0; i < 4; ++i)
      #pragma unroll
      for (int j = 0; j < 4; ++j) acc[i][j] = (f32x4){0.f,0.f,0.f,0.f};

    const char* ecc = ebase + (size_t)cc * 16384;

    for (int kw = 0; kw < 8; ++kw) {             // physical k-windows
      short8 bH[4], bL[4], aH[4], aL[4];
      #pragma unroll
      for (int j = 0; j < 4; ++j) {              // coalesced 1 KB loads (L1/L2)
        bH[j] = *(const short8*)(ecc + (size_t)kw * 262144 + j * 1024);
        bL[j] = *(const short8*)(ecc + (size_t)(kw + 8) * 262144 + j * 1024);
      }
      #pragma unroll
      for (int i = 0; i < 4; ++i) {              // LDS A fragments
        const int row = wr*64 + i*16 + cl;
        aH[i] = *(const short8*)(Zb + (size_t)row * 1024 + ((kw*64       + (g << 4)) ^ lsw));
        aL[i] = *(const short8*)(Zb + (size_t)row * 1024 + (((kw + 8)*64 + (g << 4)) ^ lsw));
      }
      __builtin_amdgcn_s_setprio(1);
      #pragma unroll
      for (int i = 0; i < 4; ++i)
        #pragma unroll
        for (int j = 0; j < 4; ++j) {
          acc[i][j] = __builtin_amdgcn_mfma_f32_16x16x32_bf16(aH[i], bH[j], acc[i][j], 0, 0, 0);
          acc[i][j] = __builtin_amdgcn_mfma_f32_16x16x32_bf16(aH[i], bL[j], acc[i][j], 0, 0, 0);
          acc[i][j] = __builtin_amdgcn_mfma_f32_16x16x32_bf16(aL[i], bH[j], acc[i][j], 0, 0, 0);
          acc[i][j] = __builtin_amdgcn_mfma_f32_16x16x32_bf16(aL[i], bL[j], acc[i][j], 0, 0, 0);
        }
      __builtin_amdgcn_s_setprio(0);
    }
    // epilogue: scores -> running argmin (codes ascend with cc, then j)
    #pragma unroll
    for (int j = 0; j < 4; ++j) {
      const int code = cc*256 + wc*64 + j*16 + cl;
      const float ee = e2g[code];
      #pragma unroll
      for (int i = 0; i < 4; ++i)
        #pragma unroll
        for (int r = 0; r < 4; ++r) {
          const float sc = ee - 2.0f * acc[i][j][r];
          if (sc < bestv[i][r]) { bestv[i][r] = sc; besti[i][r] = code; }
        }
    }
  }

  // ---- final argmin reduce: 16 lanes (code dim) then 4 wc waves ----
  struct RP { float v; int i; };
  RP* red = (RP*)(smem + 131072);    // [128][4]
  #pragma unroll
  for (int i = 0; i < 4; ++i)
    #pragma unroll
    for (int r = 0; r < 4; ++r) {
      float v = bestv[i][r]; int bi = besti[i][r];
      #pragma unroll
      for (int m = 1; m < 16; m <<= 1) {
        const float ov = __shfl_xor(v, m, 64);
        const int   oi = __shfl_xor(bi, m, 64);
        if (ov < v || (ov == v && oi < bi)) { v = ov; bi = oi; }
      }
      if ((l & 15) == 0) {
        const int tl = wr*64 + i*16 + g*4 + r;
        red[tl*4 + wc].v = v; red[tl*4 + wc].i = bi;
      }
    }
  __syncthreads();
  if (tid < 128) {
    float v = red[tid*4].v; int bi = red[tid*4].i;
    #pragma unroll
    for (int x = 1; x < 4; ++x) {
      const float ov = red[tid*4 + x].v; const int oi = red[tid*4 + x].i;
      if (ov < v || (ov == v && oi < bi)) { v = ov; bi = oi; }
    }
    zidx_i[t0 + tid] = bi;
    zidx_f[t0 + tid] = (float)bi;
  }
}

// ---------------- Kernel C: quant = e[zidx]  (f32 out) ----------------------
extern "C" __global__ __launch_bounds__(256)
void gather_quant(const float* __restrict__ e, const int* __restrict__ zidx,
                  float* __restrict__ q) {
  const int gid = blockIdx.x * 256 + threadIdx.x;
  const int t = gid >> 6;
  const int c = (gid & 63) << 2;
  const int idx = zidx[t];
  const float4 v = *(const float4*)&e[(size_t)idx * CDIM + c];
  *(float4*)&q[(size_t)t * CDIM + c] = v;
}

// ---------------- launch ----------------------------------------------------
extern "C" void kernel_launch(void* const* d_in, const int* in_sizes, int n_in,
                              void* d_out, int out_size, void* d_ws, size_t ws_size,
                              hipStream_t stream) {
  const float* encode = (const float*)d_in[0];
  const float* cb     = (const float*)d_in[1];
  const float* pw     = (const float*)d_in[2];
  const float* pb     = (const float*)d_in[3];

  float* e  = (float*)d_ws;                           // 4 MB
  float* e2 = e + (size_t)K_CODES * CDIM;             // 16 KB
  int*   zi = (int*)(e2 + K_CODES);                   // 128 KB
  unsigned short* Ect = (unsigned short*)(zi + NTOK); // 4 MB fragment-linear

  float* out     = (float*)d_out;
  float* zidx_f  = out;
  float* quant_f = out + NTOK;

  (void)hipFuncSetAttribute((const void*)score_mfma,
                            hipFuncAttributeMaxDynamicSharedMemorySize, 135168);

  proj_gemm<<<dim3(CDIM/64, K_CODES/64), 256, 0, stream>>>(cb, pw, pb, e);
  split_e<<<(K_CODES*64)/256, 256, 0, stream>>>(e, Ect, e2);
  score_mfma<<<NTOK/128, 512, 135168, stream>>>(encode, Ect, e2, zi, zidx_f);
  gather_quant<<<(NTOK*64)/256, 256, 0, stream>>>(e, zi, quant_f);
}